// Round 7
// baseline (213.608 us; speedup 1.0000x reference)
//
#include <hip/hip_runtime.h>

// ExpFlow: scaling-and-squaring exponentiation of a velocity field.
// x: [N=2, C=3, 128^3] f32. u0 = x/32; 5x: u <- u + warp(u, id+u).
//
// R14: LDS-staged gathers for s1-s3.
// Cycle accounting (R7-R13): mid-steps cost ~74K cyc/CU; VALU ~13%, L2
// bytes ~2us, HBM bytes ~8us -- but per-LANE VMEM requests (10 instr x
// 64 lanes x 128 waves ~ 82K) match. Divergent gathers process at ~1
// lane-request/cycle in the TA/TCP path regardless of layout -- the
// ~1.4 TB/s "wall" of R7-R13. Fix: move gathers to LDS (per-lane capable,
// idle all session). Warps are near-identity (disp std 0.2/0.4/0.8 vox at
// s1/s2/s3), so each 1024-thr block (128w x 4h x 4d tile) stages a 9x9-row
// region (halo +-2 in h,d; full w; 12B-pair layout identical to global;
// 62KB static LDS) via COALESCED streaming loads, then gathers from LDS.
// Out-of-halo lanes (|disp|>2: ~0%/0.01%/1% for s1/s2/s3) take a
// predicated global fallback with bitwise-identical decode. s4 (21%/lane
// out) and s5 keep the R13 global path. Packing (6B/voxel pairs), LIFO
// sweep, lerp order, numerics: identical to R11/R13 (absmax 1.95e-3).

namespace {
constexpr int kD = 128, kH = 128, kW = 128, kN = 2, kC = 3;
constexpr int kPlane = kD * kH * kW;          // 2^21 voxels per batch
constexpr int kVol   = kC * kPlane;
constexpr int kTotalVox   = kN * kPlane;      // 4,194,304
constexpr int kTotalElems = kN * kVol;        // 12,582,912 f32 (SoA buffer)
constexpr size_t kBatchBytes = (size_t)kPlane * 6;   // 12,582,912 B (pairs)
constexpr float kScale0 = 1.0f / 32.0f;
}

typedef float f32x2 __attribute__((ext_vector_type(2)));
typedef unsigned int u32;
typedef u32 u32x3 __attribute__((ext_vector_type(3), aligned(4)));
typedef u32 u32x4a4 __attribute__((ext_vector_type(4), aligned(4)));

static __device__ __forceinline__ float h2f(u32 bits) {
    _Float16 v;
    unsigned short s = (unsigned short)bits;
    __builtin_memcpy(&v, &s, 2);
    return (float)v;               // v_cvt_f32_f16
}
static __device__ __forceinline__ u32 f2h2(float a, float b) {
    _Float16 ha = (_Float16)a, hb = (_Float16)b;   // v_cvt_f16_f32 (RTN)
    unsigned short sa, sb;
    __builtin_memcpy(&sa, &ha, 2);
    __builtin_memcpy(&sb, &hb, 2);
    return (u32)sa | ((u32)sb << 16);
}
// Decode a 16B window starting at pair k, dword offset pb (0/1) into the
// two corner voxels (x0, x0+1). Identical for global and LDS sources.
static __device__ __forceinline__ void decode_pair(u32 q0, u32 q1, u32 q2, u32 q3,
                                                   u32 pb, float* a, float* bb) {
    u32 xy0 = pb ? q1 : q0;
    u32 z0b = pb ? (q0 >> 16) : (q1 & 0xffffu);
    u32 xy1 = q2;
    u32 z1b = pb ? (q3 & 0xffffu) : (q1 >> 16);
    a[0] = h2f(xy0 & 0xffffu); a[1] = h2f(xy0 >> 16); a[2] = h2f(z0b);
    bb[0] = h2f(xy1 & 0xffffu); bb[1] = h2f(xy1 >> 16); bb[2] = h2f(z1b);
}

// XCD-slab swizzle, 1024-thread blocks, tile = 128w x 4h x 4d (R13).
static __device__ __forceinline__ int slab_rr(int* n_out, bool rev) {
    int b    = blockIdx.x;                 // 0..2047
    int xcd  = b & 7;
    int seq  = b >> 3;                     // 0..255
    if (rev) seq = 255 - seq;
    int slab = xcd | (((seq >> 7) & 1) << 3);   // 0..15
    *n_out   = slab >> 3;                  // batch
    int dblk = slab & 7;
    int s7   = seq & 127;
    int ht   = s7 & 31;
    int dt   = (s7 >> 5) & 3;
    int wl   = threadIdx.x & 63;
    int hh   = (threadIdx.x >> 6) & 3;
    int dd   = (threadIdx.x >> 8) & 3;
    int d    = (dblk << 4) | (dt << 2) | dd;
    int h    = (ht << 2) | hh;
    return (d << 14) | (h << 7) | (wl << 1);
}

// ---------------------------------------------------------------------------
// Transcode: f32 SoA x (scale fused) -> pair-packed fp16 (12B/pair). nt loads.
// ---------------------------------------------------------------------------
__global__ __launch_bounds__(1024) void transcode_kernel(const float* __restrict__ x,
                                                         void* __restrict__ aos) {
    int n;
    int rr = slab_rr(&n, false);
    const float* __restrict__ ub = x + (size_t)n * kVol;
    f32x2 bx = __builtin_nontemporal_load((const f32x2*)(ub + rr));
    f32x2 by = __builtin_nontemporal_load((const f32x2*)(ub + kPlane + rr));
    f32x2 bz = __builtin_nontemporal_load((const f32x2*)(ub + 2 * kPlane + rr));
    bx *= kScale0; by *= kScale0; bz *= kScale0;
    u32x3 s;
    s.x = f2h2(bx.x, by.x);
    s.y = f2h2(bz.x, bz.y);
    s.z = f2h2(bx.y, by.y);
    char* ob = (char*)aos + (size_t)n * kBatchBytes;
    *(u32x3*)(ob + (size_t)(rr >> 1) * 12) = s;
}

// ---------------------------------------------------------------------------
// R14 LDS-staged step (s1-s3): pair-packed fp16 -> pair-packed fp16.
// Region: 9 d-rows x 9 h-rows x full w (halo +-2), 12B-pair rows (768B).
// ---------------------------------------------------------------------------
template <bool REV>
__global__ __launch_bounds__(1024) void step_lds(const void* __restrict__ uin,
                                                 void* __restrict__ uout) {
    __shared__ u32 sm[81 * 192 + 4];       // 62,224 B (pad for 16B tail read)

    int b    = blockIdx.x;
    int xcd  = b & 7;
    int seq  = b >> 3;
    if (REV) seq = 255 - seq;
    int slab = xcd | (((seq >> 7) & 1) << 3);
    int n    = slab >> 3;
    int dblk = slab & 7;
    int s7   = seq & 127;
    int ht   = s7 & 31;
    int dt   = (s7 >> 5) & 3;
    int h0   = ht << 2;
    int d0   = (dblk << 4) | (dt << 2);

    const char* __restrict__ ubase = (const char*)uin + (size_t)n * kBatchBytes;

    // --- Stage 9x9 rows (halo +-2, clamped) with coalesced 16B loads. ---
    int hs = h0 - 2, dsb = d0 - 2;
    for (int idx = threadIdx.x; idx < 81 * 48; idx += 1024) {
        int row = idx / 48;                // 0..80
        int c   = idx - row * 48;          // 16B chunk within 768B row
        int id  = row / 9;
        int ih  = row - id * 9;
        int gy  = min(max(hs + ih, 0), 127);
        int gz  = min(max(dsb + id, 0), 127);
        size_t sb = (size_t)(((gz << 13) | (gy << 6)) * 12) + (size_t)c * 16;
        u32x4a4 q = *(const u32x4a4*)(ubase + sb);
        int dw = row * 192 + c * 4;        // 16B-aligned LDS store
        sm[dw] = q.x; sm[dw + 1] = q.y; sm[dw + 2] = q.z; sm[dw + 3] = q.w;
    }
    __syncthreads();

    int wl = threadIdx.x & 63;
    int hh = (threadIdx.x >> 6) & 3;
    int dd = (threadIdx.x >> 8) & 3;
    int d  = d0 | dd;
    int h  = h0 | hh;
    int w  = wl << 1;
    int rr = (d << 14) | (h << 7) | w;

    // Base velocity from LDS (own row is staged: i_h = hh+2, i_d = dd+2).
    {
        // fallthrough block keeps b0..b2 in scope below
    }
    int rown = (dd + 2) * 9 + (hh + 2);
    int dwb  = rown * 192 + wl * 3;
    u32 b0 = sm[dwb], b1 = sm[dwb + 1], b2 = sm[dwb + 2];
    float vx[2], vy[2], vz[2];
    vx[0] = h2f(b0 & 0xffffu); vy[0] = h2f(b0 >> 16); vz[0] = h2f(b1 & 0xffffu);
    vx[1] = h2f(b2 & 0xffffu); vy[1] = h2f(b2 >> 16); vz[1] = h2f(b1 >> 16);

    // Cube offsets + weights (border clamp folded into low corner).
    int   x0a[2], y0a[2], z0a[2];
    float wxa[2], wya[2], wza[2];
    #pragma unroll
    for (int j = 0; j < 2; ++j) {
        float px = fminf(fmaxf((float)(w + j) + vx[j] * 63.5f, 0.0f), 127.0f);
        float py = fminf(fmaxf((float)h       + vy[j] * 63.5f, 0.0f), 127.0f);
        float pz = fminf(fmaxf((float)d       + vz[j] * 63.5f, 0.0f), 127.0f);
        int x0 = min((int)floorf(px), 126);
        int y0 = min((int)floorf(py), 126);
        int z0 = min((int)floorf(pz), 126);
        wxa[j] = px - (float)x0;
        wya[j] = py - (float)y0;
        wza[j] = pz - (float)z0;
        x0a[j] = x0; y0a[j] = y0; z0a[j] = z0;
    }

    const int rowbyte[4] = {0, 768, 98304, 99072};   // global-path offsets
    float res[3][2];
    #pragma unroll
    for (int j = 0; j < 2; ++j) {
        float wx = wxa[j], wy = wya[j], wz = wza[j];
        float omx = 1.0f - wx, omy = 1.0f - wy, omz = 1.0f - wz;
        int x0 = x0a[j], y0 = y0a[j], z0 = z0a[j];
        u32 pb = (u32)(x0 & 1);
        int xp = x0 >> 1;
        float cr[4][3];
        unsigned ih = (unsigned)(y0 - h0 + 2);
        unsigned id = (unsigned)(z0 - d0 + 2);
        if (ih < 8u && id < 8u) {
            // LDS gathers: rows (id,ih),(id,ih+1),(id+1,ih),(id+1,ih+1).
            int r00 = ((int)id * 9 + (int)ih) * 192 + xp * 3 + (int)pb;
            const int roff[4] = {0, 192, 9 * 192, 10 * 192};
            #pragma unroll
            for (int r = 0; r < 4; ++r) {
                int dw = r00 + roff[r];
                decode_pair(sm[dw], sm[dw + 1], sm[dw + 2], sm[dw + 3], pb,
                            cr[r], cr[r]);   // placeholder overwritten below
                float a[3], bv[3];
                decode_pair(sm[dw], sm[dw + 1], sm[dw + 2], sm[dw + 3], pb, a, bv);
                cr[r][0] = a[0] * omx + bv[0] * wx;
                cr[r][1] = a[1] * omx + bv[1] * wx;
                cr[r][2] = a[2] * omx + bv[2] * wx;
            }
        } else {
            // Rare out-of-halo: global fallback, identical decode.
            int o = (z0 << 14) + (y0 << 7) + x0;
            size_t gb = (size_t)(o >> 1) * 12 + (pb << 2);
            #pragma unroll
            for (int r = 0; r < 4; ++r) {
                u32x4a4 q = *(const u32x4a4*)(ubase + gb + rowbyte[r]);
                float a[3], bv[3];
                decode_pair(q.x, q.y, q.z, q.w, pb, a, bv);
                cr[r][0] = a[0] * omx + bv[0] * wx;
                cr[r][1] = a[1] * omx + bv[1] * wx;
                cr[r][2] = a[2] * omx + bv[2] * wx;
            }
        }
        #pragma unroll
        for (int c = 0; c < 3; ++c) {
            float c0 = cr[0][c] * omy + cr[1][c] * wy;
            float c1 = cr[2][c] * omy + cr[3][c] * wy;
            float base = (c == 0) ? vx[j] : (c == 1) ? vy[j] : vz[j];
            res[c][j] = base + (c0 * omz + c1 * wz);
        }
    }

    u32x3 s;
    s.x = f2h2(res[0][0], res[1][0]);
    s.y = f2h2(res[2][0], res[2][1]);
    s.z = f2h2(res[0][1], res[1][1]);
    char* ob = (char*)uout + (size_t)n * kBatchBytes;
    *(u32x3*)(ob + (size_t)(rr >> 1) * 12) = s;
}

// ---------------------------------------------------------------------------
// R13 global-gather step (s4, s5). MODE 1: -> pairs. MODE 2: -> f32 SoA.
// ---------------------------------------------------------------------------
template <int MODE, bool REV>
__global__ __launch_bounds__(1024) void step_p6h(const void* __restrict__ uin,
                                                 void* __restrict__ uout) {
    int n;
    int rr = slab_rr(&n, REV);
    int w = rr & 127;
    int h = (rr >> 7) & 127;
    int d = rr >> 14;

    const char* __restrict__ ubase = (const char*)uin + (size_t)n * kBatchBytes;

    u32x3 bq = *(const u32x3*)(ubase + (size_t)(rr >> 1) * 12);
    float vx[2], vy[2], vz[2];
    vx[0] = h2f(bq.x & 0xffffu); vy[0] = h2f(bq.x >> 16); vz[0] = h2f(bq.y & 0xffffu);
    vx[1] = h2f(bq.z & 0xffffu); vy[1] = h2f(bq.z >> 16); vz[1] = h2f(bq.y >> 16);

    int   o[2];
    float wxa[2], wya[2], wza[2];
    #pragma unroll
    for (int j = 0; j < 2; ++j) {
        float px = fminf(fmaxf((float)(w + j) + vx[j] * 63.5f, 0.0f), 127.0f);
        float py = fminf(fmaxf((float)h       + vy[j] * 63.5f, 0.0f), 127.0f);
        float pz = fminf(fmaxf((float)d       + vz[j] * 63.5f, 0.0f), 127.0f);
        int x0 = min((int)floorf(px), 126);
        int y0 = min((int)floorf(py), 126);
        int z0 = min((int)floorf(pz), 126);
        wxa[j] = px - (float)x0;
        wya[j] = py - (float)y0;
        wza[j] = pz - (float)z0;
        o[j] = (z0 << 14) + (y0 << 7) + x0;
    }

    const int rowbyte[4] = {0, 768, 98304, 99072};
    float res[3][2];
    #pragma unroll
    for (int j = 0; j < 2; ++j) {
        float wx = wxa[j], wy = wya[j], wz = wza[j];
        float omx = 1.0f - wx, omy = 1.0f - wy, omz = 1.0f - wz;
        u32 pb = (u32)(o[j] & 1);
        size_t gb = (size_t)(o[j] >> 1) * 12 + (pb << 2);
        float cr[4][3];
        #pragma unroll
        for (int r = 0; r < 4; ++r) {
            u32x4a4 q = *(const u32x4a4*)(ubase + gb + rowbyte[r]);
            float a[3], bv[3];
            decode_pair(q.x, q.y, q.z, q.w, pb, a, bv);
            cr[r][0] = a[0] * omx + bv[0] * wx;
            cr[r][1] = a[1] * omx + bv[1] * wx;
            cr[r][2] = a[2] * omx + bv[2] * wx;
        }
        #pragma unroll
        for (int c = 0; c < 3; ++c) {
            float c0 = cr[0][c] * omy + cr[1][c] * wy;
            float c1 = cr[2][c] * omy + cr[3][c] * wy;
            float base = (c == 0) ? vx[j] : (c == 1) ? vy[j] : vz[j];
            res[c][j] = base + (c0 * omz + c1 * wz);
        }
    }

    if constexpr (MODE == 2) {
        float* __restrict__ obp = (float*)uout + (size_t)n * kVol;
        __builtin_nontemporal_store(f32x2{res[0][0], res[0][1]}, (f32x2*)(obp + rr));
        __builtin_nontemporal_store(f32x2{res[1][0], res[1][1]}, (f32x2*)(obp + kPlane + rr));
        __builtin_nontemporal_store(f32x2{res[2][0], res[2][1]}, (f32x2*)(obp + 2 * kPlane + rr));
    } else {
        u32x3 s;
        s.x = f2h2(res[0][0], res[1][0]);
        s.y = f2h2(res[2][0], res[2][1]);
        s.z = f2h2(res[0][1], res[1][1]);
        char* ob = (char*)uout + (size_t)n * kBatchBytes;
        *(u32x3*)(ob + (size_t)(rr >> 1) * 12) = s;
    }
}

// ---------------------------------------------------------------------------
// R7 f32 SoA kernel retained verbatim as the small-workspace fallback.
// ---------------------------------------------------------------------------
template <bool SCALED>
__global__ __launch_bounds__(256) void step_kernel(const float* __restrict__ u,
                                                   float* __restrict__ out) {
    int b    = blockIdx.x;
    int xcd  = b & 7;
    int seq  = b >> 3;
    int slab = xcd | ((seq >> 9) << 3);
    int n    = slab >> 3;
    int dblk = slab & 7;
    int vo   = ((seq & 511) << 9) | (threadIdx.x << 1);
    int rr   = (dblk << 18) | vo;

    int w = rr & 127;
    int h = (rr >> 7) & 127;
    int d = rr >> 14;

    const float* __restrict__ ub = u + (size_t)n * kVol;

    f32x2 bx = *(const f32x2*)(ub + rr);
    f32x2 by = *(const f32x2*)(ub + kPlane + rr);
    f32x2 bz = *(const f32x2*)(ub + 2 * kPlane + rr);
    if (SCALED) { bx *= kScale0; by *= kScale0; bz *= kScale0; }

    int   o[2];
    float wxa[2], wya[2], wza[2];
    #pragma unroll
    for (int j = 0; j < 2; ++j) {
        float vx = (j == 0) ? bx.x : bx.y;
        float vy = (j == 0) ? by.x : by.y;
        float vz = (j == 0) ? bz.x : bz.y;
        float px = fminf(fmaxf((float)(w + j) + vx * 63.5f, 0.0f), 127.0f);
        float py = fminf(fmaxf((float)h       + vy * 63.5f, 0.0f), 127.0f);
        float pz = fminf(fmaxf((float)d       + vz * 63.5f, 0.0f), 127.0f);
        int x0 = min((int)floorf(px), 126);
        int y0 = min((int)floorf(py), 126);
        int z0 = min((int)floorf(pz), 126);
        wxa[j] = px - (float)x0;
        wya[j] = py - (float)y0;
        wza[j] = pz - (float)z0;
        o[j] = (z0 << 14) + (y0 << 7) + x0;
    }

    const int rowoff[4] = {0, 128, 16384, 16512};
    float res[3][2];
    #pragma unroll
    for (int j = 0; j < 2; ++j) {
        float wx = wxa[j], wy = wya[j], wz = wza[j];
        float omx = 1.0f - wx, omy = 1.0f - wy, omz = 1.0f - wz;
        #pragma unroll
        for (int c = 0; c < 3; ++c) {
            const float* __restrict__ up = ub + c * kPlane;
            f32x2 v00 = *(const f32x2*)(up + o[j] + rowoff[0]);
            f32x2 v01 = *(const f32x2*)(up + o[j] + rowoff[1]);
            f32x2 v10 = *(const f32x2*)(up + o[j] + rowoff[2]);
            f32x2 v11 = *(const f32x2*)(up + o[j] + rowoff[3]);
            if (SCALED) { v00 *= kScale0; v01 *= kScale0; v10 *= kScale0; v11 *= kScale0; }
            float c00 = v00.x * omx + v00.y * wx;
            float c01 = v01.x * omx + v01.y * wx;
            float c10 = v10.x * omx + v10.y * wx;
            float c11 = v11.x * omx + v11.y * wx;
            float c0 = c00 * omy + c01 * wy;
            float c1 = c10 * omy + c11 * wy;
            float s  = c0 * omz + c1 * wz;
            float base = (c == 0) ? ((j == 0) ? bx.x : bx.y)
                       : (c == 1) ? ((j == 0) ? by.x : by.y)
                                  : ((j == 0) ? bz.x : bz.y);
            res[c][j] = base + s;
        }
    }

    float* __restrict__ ob = out + (size_t)n * kVol;
    *(f32x2*)(ob + rr)              = f32x2{res[0][0], res[0][1]};
    *(f32x2*)(ob + kPlane + rr)     = f32x2{res[1][0], res[1][1]};
    *(f32x2*)(ob + 2 * kPlane + rr) = f32x2{res[2][0], res[2][1]};
}

extern "C" void kernel_launch(void* const* d_in, const int* in_sizes, int n_in,
                              void* d_out, int out_size, void* d_ws, size_t ws_size,
                              hipStream_t stream) {
    const float* x = (const float*)d_in[0];
    float* out = (float*)d_out;

    const int grd = kTotalVox / (1024 * 2);  // 2048 blocks of 1024 threads
    const size_t need_p6 = (size_t)2 * kN * kBatchBytes + 4096;

    if (ws_size >= need_p6) {
        char* A = (char*)d_ws;
        char* B = A + (size_t)kN * kBatchBytes;
        transcode_kernel<<<grd, 1024, 0, stream>>>(x, A);        // u0 (asc)
        step_lds<true ><<<grd, 1024, 0, stream>>>(A, B);         // s1 (desc, LDS)
        step_lds<false><<<grd, 1024, 0, stream>>>(B, A);         // s2 (asc, LDS)
        step_lds<true ><<<grd, 1024, 0, stream>>>(A, B);         // s3 (desc, LDS)
        step_p6h<1, false><<<grd, 1024, 0, stream>>>(B, A);      // s4 (asc, global)
        step_p6h<2, true ><<<grd, 1024, 0, stream>>>(A, out);    // s5 -> d_out
    } else {
        float* ws = (float*)d_ws;
        const int g256 = kTotalVox / (256 * 2);
        step_kernel<true ><<<g256, 256, 0, stream>>>(x,   out);
        step_kernel<false><<<g256, 256, 0, stream>>>(out, ws);
        step_kernel<false><<<g256, 256, 0, stream>>>(ws,  out);
        step_kernel<false><<<g256, 256, 0, stream>>>(out, ws);
        step_kernel<false><<<g256, 256, 0, stream>>>(ws,  out);
    }
}

// Round 8
// 213.102 us; speedup vs baseline: 1.0024x; 1.0024x over previous
//
#include <hip/hip_runtime.h>

// ExpFlow: scaling-and-squaring exponentiation of a velocity field.
// x: [N=2, C=3, 128^3] f32. u0 = x/32; 5x: u <- u + warp(u, id+u).
//
// R15: R14's LDS-staged s1-s3, with the three R14 defects removed:
//   (1) __launch_bounds__(1024, 8) caps VGPR at 64 -> 2 blocks/CU
//       (R14 likely ran 1 block/CU and lost all latency hiding);
//   (2) decode_pair called ONCE per gather (R14 called it twice -- bug);
//   (3) minimal live state in the j-loop (no index arrays, incremental
//       result packing) so the 64-VGPR cap doesn't spill.
// Model (R7-R13, unfalsified): mid-steps are bound by divergent-VMEM
// lane-requests at ~1.15 cyc/lane (8 gather instrs x 64 lanes x 128
// waves ~ 74K cyc/CU). LDS lane-slots are ~5x cheaper; staging is
// coalesced (the 6.5 TB/s access class). s1-s3 disp max ~0.5/1.1/2.2
// voxels -> halo +-2 covers ~100%/~100%/96.5% of lanes; rare out-of-halo
// lanes take the bitwise-identical global fallback. s4 (disp ~6 max) and
// s5 keep the R13 global path. Packing (6B/voxel pairs), LIFO sweep,
// lerp order, numerics: identical to R11/R13 (absmax 1.95e-3).

namespace {
constexpr int kD = 128, kH = 128, kW = 128, kN = 2, kC = 3;
constexpr int kPlane = kD * kH * kW;          // 2^21 voxels per batch
constexpr int kVol   = kC * kPlane;
constexpr int kTotalVox   = kN * kPlane;      // 4,194,304
constexpr int kTotalElems = kN * kVol;        // 12,582,912 f32 (SoA buffer)
constexpr size_t kBatchBytes = (size_t)kPlane * 6;   // 12,582,912 B (pairs)
constexpr float kScale0 = 1.0f / 32.0f;
}

typedef float f32x2 __attribute__((ext_vector_type(2)));
typedef unsigned int u32;
typedef u32 u32x3 __attribute__((ext_vector_type(3), aligned(4)));
typedef u32 u32x4a4 __attribute__((ext_vector_type(4), aligned(4)));

static __device__ __forceinline__ float h2f(u32 bits) {
    _Float16 v;
    unsigned short s = (unsigned short)bits;
    __builtin_memcpy(&v, &s, 2);
    return (float)v;               // v_cvt_f32_f16
}
static __device__ __forceinline__ u32 f2h2(float a, float b) {
    _Float16 ha = (_Float16)a, hb = (_Float16)b;   // v_cvt_f16_f32 (RTN)
    unsigned short sa, sb;
    __builtin_memcpy(&sa, &ha, 2);
    __builtin_memcpy(&sb, &hb, 2);
    return (u32)sa | ((u32)sb << 16);
}
// Decode a 16B window at dword offset pb (0/1) from a pair boundary into
// corner voxels (x0, x0+1). Identical for global and LDS sources (R11-proven).
static __device__ __forceinline__ void decode_pair(u32 q0, u32 q1, u32 q2, u32 q3,
                                                   u32 pb, float* a, float* bb) {
    u32 xy0 = pb ? q1 : q0;
    u32 z0b = pb ? (q0 >> 16) : (q1 & 0xffffu);
    u32 xy1 = q2;
    u32 z1b = pb ? (q3 & 0xffffu) : (q1 >> 16);
    a[0] = h2f(xy0 & 0xffffu); a[1] = h2f(xy0 >> 16); a[2] = h2f(z0b);
    bb[0] = h2f(xy1 & 0xffffu); bb[1] = h2f(xy1 >> 16); bb[2] = h2f(z1b);
}

// XCD-slab swizzle, 1024-thread blocks, tile = 128w x 4h x 4d (R13).
static __device__ __forceinline__ int slab_rr(int* n_out, bool rev) {
    int b    = blockIdx.x;                 // 0..2047
    int xcd  = b & 7;
    int seq  = b >> 3;                     // 0..255
    if (rev) seq = 255 - seq;
    int slab = xcd | (((seq >> 7) & 1) << 3);   // 0..15
    *n_out   = slab >> 3;                  // batch
    int dblk = slab & 7;
    int s7   = seq & 127;
    int ht   = s7 & 31;
    int dt   = (s7 >> 5) & 3;
    int wl   = threadIdx.x & 63;
    int hh   = (threadIdx.x >> 6) & 3;
    int dd   = (threadIdx.x >> 8) & 3;
    int d    = (dblk << 4) | (dt << 2) | dd;
    int h    = (ht << 2) | hh;
    return (d << 14) | (h << 7) | (wl << 1);
}

// ---------------------------------------------------------------------------
// Transcode: f32 SoA x (scale fused) -> pair-packed fp16 (12B/pair). nt loads.
// ---------------------------------------------------------------------------
__global__ __launch_bounds__(1024) void transcode_kernel(const float* __restrict__ x,
                                                         void* __restrict__ aos) {
    int n;
    int rr = slab_rr(&n, false);
    const float* __restrict__ ub = x + (size_t)n * kVol;
    f32x2 bx = __builtin_nontemporal_load((const f32x2*)(ub + rr));
    f32x2 by = __builtin_nontemporal_load((const f32x2*)(ub + kPlane + rr));
    f32x2 bz = __builtin_nontemporal_load((const f32x2*)(ub + 2 * kPlane + rr));
    bx *= kScale0; by *= kScale0; bz *= kScale0;
    u32x3 s;
    s.x = f2h2(bx.x, by.x);
    s.y = f2h2(bz.x, bz.y);
    s.z = f2h2(bx.y, by.y);
    char* ob = (char*)aos + (size_t)n * kBatchBytes;
    *(u32x3*)(ob + (size_t)(rr >> 1) * 12) = s;
}

// ---------------------------------------------------------------------------
// R15 LDS-staged step (s1-s3): pair-packed fp16 -> pair-packed fp16.
// Region: 9x9 rows (halo +-2, clamped), 12B-pair rows (768B = 192 dwords).
// __launch_bounds__(1024, 8): 8 waves/EU min -> VGPR <= 64 -> 2 blocks/CU.
// ---------------------------------------------------------------------------
template <bool REV>
__global__ __launch_bounds__(1024, 8) void step_lds(const void* __restrict__ uin,
                                                    void* __restrict__ uout) {
    __shared__ u32 sm[81 * 192 + 4];       // 62,224 B (+pad for 16B tail read)

    int b    = blockIdx.x;
    int xcd  = b & 7;
    int seq  = b >> 3;
    if (REV) seq = 255 - seq;
    int slab = xcd | (((seq >> 7) & 1) << 3);
    int n    = slab >> 3;
    int dblk = slab & 7;
    int s7   = seq & 127;
    int ht   = s7 & 31;
    int dt   = (s7 >> 5) & 3;
    int h0   = ht << 2;
    int d0   = (dblk << 4) | (dt << 2);

    const char* __restrict__ ubase = (const char*)uin + (size_t)n * kBatchBytes;

    // --- Stage 9x9 rows (halo +-2, clamped) with coalesced 16B loads. ---
    {
        int hs = h0 - 2, dsb = d0 - 2;
        for (int idx = threadIdx.x; idx < 81 * 48; idx += 1024) {
            int row = idx / 48;                // 0..80
            int c   = idx - row * 48;          // 16B chunk within 768B row
            int id  = row / 9;
            int ih  = row - id * 9;
            int gy  = min(max(hs + ih, 0), 127);
            int gz  = min(max(dsb + id, 0), 127);
            size_t sb = (size_t)(((gz << 13) | (gy << 6)) * 12) + (size_t)c * 16;
            u32x4a4 q = *(const u32x4a4*)(ubase + sb);
            int dw = row * 192 + c * 4;        // 16B-aligned LDS store
            sm[dw] = q.x; sm[dw + 1] = q.y; sm[dw + 2] = q.z; sm[dw + 3] = q.w;
        }
    }
    __syncthreads();

    int wl = threadIdx.x & 63;
    int hh = (threadIdx.x >> 6) & 3;
    int dd = (threadIdx.x >> 8) & 3;
    int d  = d0 | dd;
    int h  = h0 | hh;
    int w  = wl << 1;
    int rr = (d << 14) | (h << 7) | w;

    // Base velocity from LDS (own row: i_h = hh+2, i_d = dd+2; pb = 0).
    int dwb = ((dd + 2) * 9 + (hh + 2)) * 192 + wl * 3;
    u32 b0 = sm[dwb], b1 = sm[dwb + 1], b2 = sm[dwb + 2];
    float vx[2], vy[2], vz[2];
    vx[0] = h2f(b0 & 0xffffu); vy[0] = h2f(b0 >> 16); vz[0] = h2f(b1 & 0xffffu);
    vx[1] = h2f(b2 & 0xffffu); vy[1] = h2f(b2 >> 16); vz[1] = h2f(b1 >> 16);

    float r00, r10, r20;                   // j=0 results carried across j-loop
    u32x3 sout;
    const int rowbyte[4] = {0, 768, 98304, 99072};   // global-fallback offsets
    #pragma unroll
    for (int j = 0; j < 2; ++j) {
        float px = fminf(fmaxf((float)(w + j) + vx[j] * 63.5f, 0.0f), 127.0f);
        float py = fminf(fmaxf((float)h       + vy[j] * 63.5f, 0.0f), 127.0f);
        float pz = fminf(fmaxf((float)d       + vz[j] * 63.5f, 0.0f), 127.0f);
        int x0 = min((int)floorf(px), 126);
        int y0 = min((int)floorf(py), 126);
        int z0 = min((int)floorf(pz), 126);
        float wx = px - (float)x0, wy = py - (float)y0, wz = pz - (float)z0;
        float omx = 1.0f - wx, omy = 1.0f - wy, omz = 1.0f - wz;
        u32 pb = (u32)(x0 & 1);

        float cr[4][3];
        unsigned ih = (unsigned)(y0 - h0 + 2);
        unsigned id = (unsigned)(z0 - d0 + 2);
        if ((ih < 8u) & (id < 8u)) {
            // LDS gathers: rows (id,ih),(id,ih+1),(id+1,ih),(id+1,ih+1).
            int r0dw = ((int)id * 9 + (int)ih) * 192 + (x0 >> 1) * 3 + (int)pb;
            const int roff[4] = {0, 192, 9 * 192, 10 * 192};
            #pragma unroll
            for (int r = 0; r < 4; ++r) {
                int dw = r0dw + roff[r];
                float a[3], bv[3];
                decode_pair(sm[dw], sm[dw + 1], sm[dw + 2], sm[dw + 3], pb, a, bv);
                cr[r][0] = a[0] * omx + bv[0] * wx;
                cr[r][1] = a[1] * omx + bv[1] * wx;
                cr[r][2] = a[2] * omx + bv[2] * wx;
            }
        } else {
            // Rare out-of-halo: global fallback, identical decode.
            int o = (z0 << 14) + (y0 << 7) + x0;
            size_t gb = (size_t)(o >> 1) * 12 + (pb << 2);
            #pragma unroll
            for (int r = 0; r < 4; ++r) {
                u32x4a4 q = *(const u32x4a4*)(ubase + gb + rowbyte[r]);
                float a[3], bv[3];
                decode_pair(q.x, q.y, q.z, q.w, pb, a, bv);
                cr[r][0] = a[0] * omx + bv[0] * wx;
                cr[r][1] = a[1] * omx + bv[1] * wx;
                cr[r][2] = a[2] * omx + bv[2] * wx;
            }
        }
        float c0x = cr[0][0] * omy + cr[1][0] * wy;
        float c1x = cr[2][0] * omy + cr[3][0] * wy;
        float c0y = cr[0][1] * omy + cr[1][1] * wy;
        float c1y = cr[2][1] * omy + cr[3][1] * wy;
        float c0z = cr[0][2] * omy + cr[1][2] * wy;
        float c1z = cr[2][2] * omy + cr[3][2] * wy;
        float rx = vx[j] + (c0x * omz + c1x * wz);
        float ry = vy[j] + (c0y * omz + c1y * wz);
        float rz = vz[j] + (c0z * omz + c1z * wz);
        if (j == 0) { r00 = rx; r10 = ry; r20 = rz; }
        else {
            sout.x = f2h2(r00, r10);
            sout.y = f2h2(r20, rz);
            sout.z = f2h2(rx, ry);
        }
    }
    char* ob = (char*)uout + (size_t)n * kBatchBytes;
    *(u32x3*)(ob + (size_t)(rr >> 1) * 12) = sout;
}

// ---------------------------------------------------------------------------
// R13 global-gather step (s4, s5). MODE 1: -> pairs. MODE 2: -> f32 SoA.
// ---------------------------------------------------------------------------
template <int MODE, bool REV>
__global__ __launch_bounds__(1024) void step_p6h(const void* __restrict__ uin,
                                                 void* __restrict__ uout) {
    int n;
    int rr = slab_rr(&n, REV);
    int w = rr & 127;
    int h = (rr >> 7) & 127;
    int d = rr >> 14;

    const char* __restrict__ ubase = (const char*)uin + (size_t)n * kBatchBytes;

    u32x3 bq = *(const u32x3*)(ubase + (size_t)(rr >> 1) * 12);
    float vx[2], vy[2], vz[2];
    vx[0] = h2f(bq.x & 0xffffu); vy[0] = h2f(bq.x >> 16); vz[0] = h2f(bq.y & 0xffffu);
    vx[1] = h2f(bq.z & 0xffffu); vy[1] = h2f(bq.z >> 16); vz[1] = h2f(bq.y >> 16);

    int   o[2];
    float wxa[2], wya[2], wza[2];
    #pragma unroll
    for (int j = 0; j < 2; ++j) {
        float px = fminf(fmaxf((float)(w + j) + vx[j] * 63.5f, 0.0f), 127.0f);
        float py = fminf(fmaxf((float)h       + vy[j] * 63.5f, 0.0f), 127.0f);
        float pz = fminf(fmaxf((float)d       + vz[j] * 63.5f, 0.0f), 127.0f);
        int x0 = min((int)floorf(px), 126);
        int y0 = min((int)floorf(py), 126);
        int z0 = min((int)floorf(pz), 126);
        wxa[j] = px - (float)x0;
        wya[j] = py - (float)y0;
        wza[j] = pz - (float)z0;
        o[j] = (z0 << 14) + (y0 << 7) + x0;
    }

    const int rowbyte[4] = {0, 768, 98304, 99072};
    float res[3][2];
    #pragma unroll
    for (int j = 0; j < 2; ++j) {
        float wx = wxa[j], wy = wya[j], wz = wza[j];
        float omx = 1.0f - wx, omy = 1.0f - wy, omz = 1.0f - wz;
        u32 pb = (u32)(o[j] & 1);
        size_t gb = (size_t)(o[j] >> 1) * 12 + (pb << 2);
        float cr[4][3];
        #pragma unroll
        for (int r = 0; r < 4; ++r) {
            u32x4a4 q = *(const u32x4a4*)(ubase + gb + rowbyte[r]);
            float a[3], bv[3];
            decode_pair(q.x, q.y, q.z, q.w, pb, a, bv);
            cr[r][0] = a[0] * omx + bv[0] * wx;
            cr[r][1] = a[1] * omx + bv[1] * wx;
            cr[r][2] = a[2] * omx + bv[2] * wx;
        }
        #pragma unroll
        for (int c = 0; c < 3; ++c) {
            float c0 = cr[0][c] * omy + cr[1][c] * wy;
            float c1 = cr[2][c] * omy + cr[3][c] * wy;
            float base = (c == 0) ? vx[j] : (c == 1) ? vy[j] : vz[j];
            res[c][j] = base + (c0 * omz + c1 * wz);
        }
    }

    if constexpr (MODE == 2) {
        float* __restrict__ obp = (float*)uout + (size_t)n * kVol;
        __builtin_nontemporal_store(f32x2{res[0][0], res[0][1]}, (f32x2*)(obp + rr));
        __builtin_nontemporal_store(f32x2{res[1][0], res[1][1]}, (f32x2*)(obp + kPlane + rr));
        __builtin_nontemporal_store(f32x2{res[2][0], res[2][1]}, (f32x2*)(obp + 2 * kPlane + rr));
    } else {
        u32x3 s;
        s.x = f2h2(res[0][0], res[1][0]);
        s.y = f2h2(res[2][0], res[2][1]);
        s.z = f2h2(res[0][1], res[1][1]);
        char* ob = (char*)uout + (size_t)n * kBatchBytes;
        *(u32x3*)(ob + (size_t)(rr >> 1) * 12) = s;
    }
}

// ---------------------------------------------------------------------------
// R7 f32 SoA kernel retained verbatim as the small-workspace fallback.
// ---------------------------------------------------------------------------
template <bool SCALED>
__global__ __launch_bounds__(256) void step_kernel(const float* __restrict__ u,
                                                   float* __restrict__ out) {
    int b    = blockIdx.x;
    int xcd  = b & 7;
    int seq  = b >> 3;
    int slab = xcd | ((seq >> 9) << 3);
    int n    = slab >> 3;
    int dblk = slab & 7;
    int vo   = ((seq & 511) << 9) | (threadIdx.x << 1);
    int rr   = (dblk << 18) | vo;

    int w = rr & 127;
    int h = (rr >> 7) & 127;
    int d = rr >> 14;

    const float* __restrict__ ub = u + (size_t)n * kVol;

    f32x2 bx = *(const f32x2*)(ub + rr);
    f32x2 by = *(const f32x2*)(ub + kPlane + rr);
    f32x2 bz = *(const f32x2*)(ub + 2 * kPlane + rr);
    if (SCALED) { bx *= kScale0; by *= kScale0; bz *= kScale0; }

    int   o[2];
    float wxa[2], wya[2], wza[2];
    #pragma unroll
    for (int j = 0; j < 2; ++j) {
        float vx = (j == 0) ? bx.x : bx.y;
        float vy = (j == 0) ? by.x : by.y;
        float vz = (j == 0) ? bz.x : bz.y;
        float px = fminf(fmaxf((float)(w + j) + vx * 63.5f, 0.0f), 127.0f);
        float py = fminf(fmaxf((float)h       + vy * 63.5f, 0.0f), 127.0f);
        float pz = fminf(fmaxf((float)d       + vz * 63.5f, 0.0f), 127.0f);
        int x0 = min((int)floorf(px), 126);
        int y0 = min((int)floorf(py), 126);
        int z0 = min((int)floorf(pz), 126);
        wxa[j] = px - (float)x0;
        wya[j] = py - (float)y0;
        wza[j] = pz - (float)z0;
        o[j] = (z0 << 14) + (y0 << 7) + x0;
    }

    const int rowoff[4] = {0, 128, 16384, 16512};
    float res[3][2];
    #pragma unroll
    for (int j = 0; j < 2; ++j) {
        float wx = wxa[j], wy = wya[j], wz = wza[j];
        float omx = 1.0f - wx, omy = 1.0f - wy, omz = 1.0f - wz;
        #pragma unroll
        for (int c = 0; c < 3; ++c) {
            const float* __restrict__ up = ub + c * kPlane;
            f32x2 v00 = *(const f32x2*)(up + o[j] + rowoff[0]);
            f32x2 v01 = *(const f32x2*)(up + o[j] + rowoff[1]);
            f32x2 v10 = *(const f32x2*)(up + o[j] + rowoff[2]);
            f32x2 v11 = *(const f32x2*)(up + o[j] + rowoff[3]);
            if (SCALED) { v00 *= kScale0; v01 *= kScale0; v10 *= kScale0; v11 *= kScale0; }
            float c00 = v00.x * omx + v00.y * wx;
            float c01 = v01.x * omx + v01.y * wx;
            float c10 = v10.x * omx + v10.y * wx;
            float c11 = v11.x * omx + v11.y * wx;
            float c0 = c00 * omy + c01 * wy;
            float c1 = c10 * omy + c11 * wy;
            float s  = c0 * omz + c1 * wz;
            float base = (c == 0) ? ((j == 0) ? bx.x : bx.y)
                       : (c == 1) ? ((j == 0) ? by.x : by.y)
                                  : ((j == 0) ? bz.x : bz.y);
            res[c][j] = base + s;
        }
    }

    float* __restrict__ ob = out + (size_t)n * kVol;
    *(f32x2*)(ob + rr)              = f32x2{res[0][0], res[0][1]};
    *(f32x2*)(ob + kPlane + rr)     = f32x2{res[1][0], res[1][1]};
    *(f32x2*)(ob + 2 * kPlane + rr) = f32x2{res[2][0], res[2][1]};
}

extern "C" void kernel_launch(void* const* d_in, const int* in_sizes, int n_in,
                              void* d_out, int out_size, void* d_ws, size_t ws_size,
                              hipStream_t stream) {
    const float* x = (const float*)d_in[0];
    float* out = (float*)d_out;

    const int grd = kTotalVox / (1024 * 2);  // 2048 blocks of 1024 threads
    const size_t need_p6 = (size_t)2 * kN * kBatchBytes + 4096;

    if (ws_size >= need_p6) {
        char* A = (char*)d_ws;
        char* B = A + (size_t)kN * kBatchBytes;
        transcode_kernel<<<grd, 1024, 0, stream>>>(x, A);        // u0 (asc)
        step_lds<true ><<<grd, 1024, 0, stream>>>(A, B);         // s1 (desc, LDS)
        step_lds<false><<<grd, 1024, 0, stream>>>(B, A);         // s2 (asc, LDS)
        step_lds<true ><<<grd, 1024, 0, stream>>>(A, B);         // s3 (desc, LDS)
        step_p6h<1, false><<<grd, 1024, 0, stream>>>(B, A);      // s4 (asc, global)
        step_p6h<2, true ><<<grd, 1024, 0, stream>>>(A, out);    // s5 -> d_out
    } else {
        float* ws = (float*)d_ws;
        const int g256 = kTotalVox / (256 * 2);
        step_kernel<true ><<<g256, 256, 0, stream>>>(x,   out);
        step_kernel<false><<<g256, 256, 0, stream>>>(out, ws);
        step_kernel<false><<<g256, 256, 0, stream>>>(ws,  out);
        step_kernel<false><<<g256, 256, 0, stream>>>(out, ws);
        step_kernel<false><<<g256, 256, 0, stream>>>(ws,  out);
    }
}

// Round 9
// 202.646 us; speedup vs baseline: 1.0541x; 1.0516x over previous
//
#include <hip/hip_runtime.h>

// ExpFlow: scaling-and-squaring exponentiation of a velocity field.
// x: [N=2, C=3, 128^3] f32. u0 = x/32; 5x: u <- u + warp(u, id+u).
//
// R16 = R13 verbatim (best measured: 202.3 us). R14/R15 falsified the
// LDS-staging family (properly executed in R15: VGPR<=64, single decode
// -> still slower than global gathers). Surviving model: composite
// TA/TCP transaction floor, ~6 (lane,line) transactions/voxel at
// ~1/cy/CU -> ~31 us/mid-step; all byte/instr/locality/LDS levers
// exhausted. This locks in the optimum configuration:
//   - pair-packed fp16 (6 B/voxel) ping-pong in d_ws;
//   - XCD-slab swizzle, 1024-thr blocks, 128w x 4h x 4d tiles, LIFO sweep;
//   - nt loads of x (transcode) / nt stores of d_out (s5);
//   - s5 gathers + writes f32 SoA d_out directly (single final pass).
// Numerics: fp16 intermediate storage, f32 arithmetic (absmax 1.95e-3).

namespace {
constexpr int kD = 128, kH = 128, kW = 128, kN = 2, kC = 3;
constexpr int kPlane = kD * kH * kW;          // 2^21 voxels per batch
constexpr int kVol   = kC * kPlane;
constexpr int kTotalVox   = kN * kPlane;      // 4,194,304
constexpr int kTotalElems = kN * kVol;        // 12,582,912 f32 (SoA buffer)
constexpr size_t kBatchBytes = (size_t)kPlane * 6;   // 12,582,912 B (pairs)
constexpr float kScale0 = 1.0f / 32.0f;
}

typedef float f32x2 __attribute__((ext_vector_type(2)));
typedef unsigned int u32;
typedef u32 u32x3 __attribute__((ext_vector_type(3), aligned(4)));
typedef u32 u32x4a4 __attribute__((ext_vector_type(4), aligned(4)));

static __device__ __forceinline__ float h2f(u32 bits) {
    _Float16 v;
    unsigned short s = (unsigned short)bits;
    __builtin_memcpy(&v, &s, 2);
    return (float)v;               // v_cvt_f32_f16
}
static __device__ __forceinline__ u32 f2h2(float a, float b) {
    _Float16 ha = (_Float16)a, hb = (_Float16)b;   // v_cvt_f16_f32 (RTN)
    unsigned short sa, sb;
    __builtin_memcpy(&sa, &ha, 2);
    __builtin_memcpy(&sb, &hb, 2);
    return (u32)sa | ((u32)sb << 16);
}

// XCD-slab swizzle, 1024-thread blocks, tile = 128w x 4h x 4d.
// 2048 blocks; b&7 = XCD (HW round-robin); 16 slabs (2 batches x 8
// d-slabs of 16 planes); XCD j owns slabs j, j+8. Within a slab:
// 4 d-tiles x 32 h-tiles; within a block: tid = [dd:2][hh:2][wl:6].
// REV flips the per-XCD sweep (LIFO between consecutive steps).
static __device__ __forceinline__ int slab_rr(int* n_out, bool rev) {
    int b    = blockIdx.x;                 // 0..2047
    int xcd  = b & 7;
    int seq  = b >> 3;                     // 0..255
    if (rev) seq = 255 - seq;
    int slab = xcd | (((seq >> 7) & 1) << 3);   // 0..15
    *n_out   = slab >> 3;                  // batch
    int dblk = slab & 7;                   // d-slab within batch
    int s7   = seq & 127;
    int ht   = s7 & 31;                    // h-tile
    int dt   = (s7 >> 5) & 3;              // d-tile within slab
    int wl   = threadIdx.x & 63;
    int hh   = (threadIdx.x >> 6) & 3;
    int dd   = (threadIdx.x >> 8) & 3;
    int d    = (dblk << 4) | (dt << 2) | dd;
    int h    = (ht << 2) | hh;
    return (d << 14) | (h << 7) | (wl << 1);   // within-batch even voxel
}

// ---------------------------------------------------------------------------
// Transcode: f32 SoA x (scale fused) -> pair-packed fp16 (12B/pair).
// nt loads: x is read exactly once; don't evict packed buffers from L2.
// ---------------------------------------------------------------------------
__global__ __launch_bounds__(1024) void transcode_kernel(const float* __restrict__ x,
                                                         void* __restrict__ aos) {
    int n;
    int rr = slab_rr(&n, false);
    const float* __restrict__ ub = x + (size_t)n * kVol;
    f32x2 bx = __builtin_nontemporal_load((const f32x2*)(ub + rr));
    f32x2 by = __builtin_nontemporal_load((const f32x2*)(ub + kPlane + rr));
    f32x2 bz = __builtin_nontemporal_load((const f32x2*)(ub + 2 * kPlane + rr));
    bx *= kScale0; by *= kScale0; bz *= kScale0;
    u32x3 s;
    s.x = f2h2(bx.x, by.x);      // x0,y0
    s.y = f2h2(bz.x, bz.y);      // z0,z1
    s.z = f2h2(bx.y, by.y);      // x1,y1
    char* ob = (char*)aos + (size_t)n * kBatchBytes;
    *(u32x3*)(ob + (size_t)(rr >> 1) * 12) = s;    // 12B store, 4B-aligned
}

// ---------------------------------------------------------------------------
// Warp step on pair-packed fp16. MODE 1: -> pairs. MODE 2: -> f32 SoA
// d_out (final, nontemporal stores).
// ---------------------------------------------------------------------------
template <int MODE, bool REV>
__global__ __launch_bounds__(1024) void step_p6h(const void* __restrict__ uin,
                                                 void* __restrict__ uout) {
    int n;
    int rr = slab_rr(&n, REV);
    int w = rr & 127;
    int h = (rr >> 7) & 127;
    int d = rr >> 14;

    const char* __restrict__ ubase = (const char*)uin + (size_t)n * kBatchBytes;

    // Base velocity for voxels (rr, rr+1): one 12B dwordx3 (even pair:
    // d0=x0y0, d1=z0z1, d2=x1y1).
    u32x3 bq = *(const u32x3*)(ubase + (size_t)(rr >> 1) * 12);
    float vx[2], vy[2], vz[2];
    vx[0] = h2f(bq.x & 0xffffu); vy[0] = h2f(bq.x >> 16); vz[0] = h2f(bq.y & 0xffffu);
    vx[1] = h2f(bq.z & 0xffffu); vy[1] = h2f(bq.z >> 16); vz[1] = h2f(bq.y >> 16);

    // Cube offsets + weights (border clamp folded into low corner).
    int   o[2];
    float wxa[2], wya[2], wza[2];
    #pragma unroll
    for (int j = 0; j < 2; ++j) {
        float px = fminf(fmaxf((float)(w + j) + vx[j] * 63.5f, 0.0f), 127.0f);
        float py = fminf(fmaxf((float)h       + vy[j] * 63.5f, 0.0f), 127.0f);
        float pz = fminf(fmaxf((float)d       + vz[j] * 63.5f, 0.0f), 127.0f);
        int x0 = min((int)floorf(px), 126);
        int y0 = min((int)floorf(py), 126);
        int z0 = min((int)floorf(pz), 126);
        wxa[j] = px - (float)x0;
        wya[j] = py - (float)y0;
        wza[j] = pz - (float)z0;
        o[j] = (z0 << 14) + (y0 << 7) + x0;
    }

    // Row byte offsets: +128 voxels = 64 pairs = 768B; +16384 voxels = 98304B.
    const int rowbyte[4] = {0, 768, 98304, 99072};
    float res[3][2];
    #pragma unroll
    for (int j = 0; j < 2; ++j) {
        float wx = wxa[j], wy = wya[j], wz = wza[j];
        float omx = 1.0f - wx, omy = 1.0f - wy, omz = 1.0f - wz;
        u32 pb = (u32)(o[j] & 1);
        size_t gb = (size_t)(o[j] >> 1) * 12 + (pb << 2);
        float cr[4][3];
        #pragma unroll
        for (int r = 0; r < 4; ++r) {
            u32x4a4 q = *(const u32x4a4*)(ubase + gb + rowbyte[r]);
            // even (pb=0): q = d0(k) d1(k) d2(k) d0(k+1)
            // odd  (pb=1): q = d1(k) d2(k) d0(k+1) d1(k+1)
            u32 xy0 = pb ? q.y : q.x;
            u32 z0b = pb ? (q.x >> 16) : (q.y & 0xffffu);
            u32 xy1 = q.z;
            u32 z1b = pb ? (q.w & 0xffffu) : (q.y >> 16);
            float ax = h2f(xy0 & 0xffffu), ay = h2f(xy0 >> 16), az = h2f(z0b);
            float bx = h2f(xy1 & 0xffffu), by = h2f(xy1 >> 16), bz = h2f(z1b);
            cr[r][0] = ax * omx + bx * wx;
            cr[r][1] = ay * omx + by * wx;
            cr[r][2] = az * omx + bz * wx;
        }
        #pragma unroll
        for (int c = 0; c < 3; ++c) {
            float c0 = cr[0][c] * omy + cr[1][c] * wy;
            float c1 = cr[2][c] * omy + cr[3][c] * wy;
            float base = (c == 0) ? vx[j] : (c == 1) ? vy[j] : vz[j];
            res[c][j] = base + (c0 * omz + c1 * wz);
        }
    }

    if constexpr (MODE == 2) {
        // Final step: f32 SoA into d_out (written exactly once, never read
        // again on-device) -- nontemporal to protect the A-buffer's L2 lines.
        float* __restrict__ obp = (float*)uout + (size_t)n * kVol;
        __builtin_nontemporal_store(f32x2{res[0][0], res[0][1]}, (f32x2*)(obp + rr));
        __builtin_nontemporal_store(f32x2{res[1][0], res[1][1]}, (f32x2*)(obp + kPlane + rr));
        __builtin_nontemporal_store(f32x2{res[2][0], res[2][1]}, (f32x2*)(obp + 2 * kPlane + rr));
    } else {
        u32x3 s;
        s.x = f2h2(res[0][0], res[1][0]);   // x0,y0
        s.y = f2h2(res[2][0], res[2][1]);   // z0,z1
        s.z = f2h2(res[0][1], res[1][1]);   // x1,y1
        char* ob = (char*)uout + (size_t)n * kBatchBytes;
        *(u32x3*)(ob + (size_t)(rr >> 1) * 12) = s;
    }
}

// ---------------------------------------------------------------------------
// R7 f32 SoA kernel retained verbatim as the small-workspace fallback.
// ---------------------------------------------------------------------------
template <bool SCALED>
__global__ __launch_bounds__(256) void step_kernel(const float* __restrict__ u,
                                                   float* __restrict__ out) {
    int b    = blockIdx.x;
    int xcd  = b & 7;
    int seq  = b >> 3;
    int slab = xcd | ((seq >> 9) << 3);
    int n    = slab >> 3;
    int dblk = slab & 7;
    int vo   = ((seq & 511) << 9) | (threadIdx.x << 1);
    int rr   = (dblk << 18) | vo;

    int w = rr & 127;
    int h = (rr >> 7) & 127;
    int d = rr >> 14;

    const float* __restrict__ ub = u + (size_t)n * kVol;

    f32x2 bx = *(const f32x2*)(ub + rr);
    f32x2 by = *(const f32x2*)(ub + kPlane + rr);
    f32x2 bz = *(const f32x2*)(ub + 2 * kPlane + rr);
    if (SCALED) { bx *= kScale0; by *= kScale0; bz *= kScale0; }

    int   o[2];
    float wxa[2], wya[2], wza[2];
    #pragma unroll
    for (int j = 0; j < 2; ++j) {
        float vx = (j == 0) ? bx.x : bx.y;
        float vy = (j == 0) ? by.x : by.y;
        float vz = (j == 0) ? bz.x : bz.y;
        float px = fminf(fmaxf((float)(w + j) + vx * 63.5f, 0.0f), 127.0f);
        float py = fminf(fmaxf((float)h       + vy * 63.5f, 0.0f), 127.0f);
        float pz = fminf(fmaxf((float)d       + vz * 63.5f, 0.0f), 127.0f);
        int x0 = min((int)floorf(px), 126);
        int y0 = min((int)floorf(py), 126);
        int z0 = min((int)floorf(pz), 126);
        wxa[j] = px - (float)x0;
        wya[j] = py - (float)y0;
        wza[j] = pz - (float)z0;
        o[j] = (z0 << 14) + (y0 << 7) + x0;
    }

    const int rowoff[4] = {0, 128, 16384, 16512};
    float res[3][2];
    #pragma unroll
    for (int j = 0; j < 2; ++j) {
        float wx = wxa[j], wy = wya[j], wz = wza[j];
        float omx = 1.0f - wx, omy = 1.0f - wy, omz = 1.0f - wz;
        #pragma unroll
        for (int c = 0; c < 3; ++c) {
            const float* __restrict__ up = ub + c * kPlane;
            f32x2 v00 = *(const f32x2*)(up + o[j] + rowoff[0]);
            f32x2 v01 = *(const f32x2*)(up + o[j] + rowoff[1]);
            f32x2 v10 = *(const f32x2*)(up + o[j] + rowoff[2]);
            f32x2 v11 = *(const f32x2*)(up + o[j] + rowoff[3]);
            if (SCALED) { v00 *= kScale0; v01 *= kScale0; v10 *= kScale0; v11 *= kScale0; }
            float c00 = v00.x * omx + v00.y * wx;
            float c01 = v01.x * omx + v01.y * wx;
            float c10 = v10.x * omx + v10.y * wx;
            float c11 = v11.x * omx + v11.y * wx;
            float c0 = c00 * omy + c01 * wy;
            float c1 = c10 * omy + c11 * wy;
            float s  = c0 * omz + c1 * wz;
            float base = (c == 0) ? ((j == 0) ? bx.x : bx.y)
                       : (c == 1) ? ((j == 0) ? by.x : by.y)
                                  : ((j == 0) ? bz.x : bz.y);
            res[c][j] = base + s;
        }
    }

    float* __restrict__ ob = out + (size_t)n * kVol;
    *(f32x2*)(ob + rr)              = f32x2{res[0][0], res[0][1]};
    *(f32x2*)(ob + kPlane + rr)     = f32x2{res[1][0], res[1][1]};
    *(f32x2*)(ob + 2 * kPlane + rr) = f32x2{res[2][0], res[2][1]};
}

extern "C" void kernel_launch(void* const* d_in, const int* in_sizes, int n_in,
                              void* d_out, int out_size, void* d_ws, size_t ws_size,
                              hipStream_t stream) {
    const float* x = (const float*)d_in[0];
    float* out = (float*)d_out;

    const int grd = kTotalVox / (1024 * 2);  // 2048 blocks of 1024 threads
    // Two pair-packed buffers: 2 x 25,165,824 B (+4KB slack).
    const size_t need_p6 = (size_t)2 * kN * kBatchBytes + 4096;

    if (ws_size >= need_p6) {
        char* A = (char*)d_ws;
        char* B = A + (size_t)kN * kBatchBytes;
        transcode_kernel<<<grd, 1024, 0, stream>>>(x, A);        // u0 (asc)
        step_p6h<1, true ><<<grd, 1024, 0, stream>>>(A, B);      // s1 (desc)
        step_p6h<1, false><<<grd, 1024, 0, stream>>>(B, A);      // s2 (asc)
        step_p6h<1, true ><<<grd, 1024, 0, stream>>>(A, B);      // s3 (desc)
        step_p6h<1, false><<<grd, 1024, 0, stream>>>(B, A);      // s4 (asc)
        step_p6h<2, true ><<<grd, 1024, 0, stream>>>(A, out);    // s5 -> d_out
    } else {
        // R3-parity f32 fallback: x->out->ws->out->ws->out.
        float* ws = (float*)d_ws;
        const int g256 = kTotalVox / (256 * 2);
        step_kernel<true ><<<g256, 256, 0, stream>>>(x,   out);
        step_kernel<false><<<g256, 256, 0, stream>>>(out, ws);
        step_kernel<false><<<g256, 256, 0, stream>>>(ws,  out);
        step_kernel<false><<<g256, 256, 0, stream>>>(out, ws);
        step_kernel<false><<<g256, 256, 0, stream>>>(ws,  out);
    }
}